// Round 1
// baseline (473.210 us; speedup 1.0000x reference)
//
#include <hip/hip_runtime.h>

#define NEGS  0.01f
#define LNEPS 1e-5f

typedef __attribute__((ext_vector_type(8))) short          bf16x8;
typedef __attribute__((ext_vector_type(8))) unsigned short u16x8;
typedef __attribute__((ext_vector_type(4))) unsigned short u16x4;
typedef __attribute__((ext_vector_type(4))) float          f32x4;
typedef __attribute__((ext_vector_type(4))) unsigned int   u32x4;

#define MFMA16(a, b, c) __builtin_amdgcn_mfma_f32_16x16x32_bf16((a), (b), (c), 0, 0, 0)

// workspace byte offsets (total ~9.3 MB)
#define WS_W2T  0          // 64 * 131072 bf16 blobs, pre-swizzled linear
#define WS_W1OT 8388608    // 64*256*8 bf16  : W1o^T[n][k]
#define WS_C1   8650752    // 64*256 f32     : W1[s][s,:]+b1
#define WS_WPT  8716288    // 64*16*256 bf16 : Wp^T[a][k]
#define WS_MIDX 9240576    // 512 int        : masked neighbor idx (-1 = masked)

__device__ __forceinline__ unsigned short f2bf(float v) {
  union { float f; unsigned u; } a; a.f = v;
  unsigned r = a.u + 0x7fffu + ((a.u >> 16) & 1u);   // RTNE
  return (unsigned short)(r >> 16);
}

// ---- P1: mask format detect + masked index table --------------------------
__global__ void prep_midx_k(const int* __restrict__ oidx,
                            const unsigned* __restrict__ mask32,
                            int* __restrict__ midx) {
  __shared__ int fgt1, ffl;
  const int t = threadIdx.x;            // 512 threads
  if (t == 0) { fgt1 = 0; ffl = 0; }
  __syncthreads();
  if (t < 128) {                        // safe to read 512B in all layouts
    unsigned wv = mask32[t];
    if (wv == 0x3f800000u) atomicOr(&ffl, 1);       // float 1.0 pattern
    else if (wv > 1u)      atomicOr(&fgt1, 1);      // packed bytes
  }
  __syncthreads();
  const int mode = ffl ? 2 : (fgt1 ? 1 : 0);
  int mv;
  if (mode == 2)      mv = (((const float*)mask32)[t] != 0.0f) ? 1 : 0;
  else if (mode == 1) mv = (int)((const unsigned char*)mask32)[t];
  else                mv = ((const int*)mask32)[t];
  midx[t] = (mv != 0) ? oidx[t] : -1;
}

// ---- P2: W2 -> bf16 W2^T blob with LDS swizzle baked (linear staging) -----
__global__ void prep_w2t_k(const float* __restrict__ W2, unsigned* __restrict__ w2t) {
  const int tid = blockIdx.x * 256 + threadIdx.x;   // 2,097,152 total
  const int s   = tid >> 15;
  const int wrd = tid & 32767;
  const int a   = wrd * 4;                          // byte addr within blob
  const int n   = a >> 9;
  const int x0  = (a & 511) ^ ((n & 7) << 4);
  const int k0  = x0 >> 1;                          // even
  const float* w = W2 + (size_t)s * 65536;          // [k][n]
  unsigned lo = f2bf(w[k0 * 256 + n]);
  unsigned hi = f2bf(w[(k0 + 1) * 256 + n]);
  w2t[(size_t)s * 32768 + wrd] = lo | (hi << 16);
}

// ---- P3: W1o^T + c1 -------------------------------------------------------
__global__ void prep_w1_k(const float* __restrict__ W1, const float* __restrict__ b1,
                          unsigned short* __restrict__ w1ot, float* __restrict__ c1) {
  const int tid = blockIdx.x * 256 + threadIdx.x;   // 16384
  const int s = tid >> 8, n = tid & 255;
  const float* base = W1 + (size_t)(s * 72) * 256 + n;
  c1[tid] = base[s * 256] + b1[tid];
  u16x8 v;
#pragma unroll
  for (int j = 0; j < 8; ++j) v[j] = f2bf(base[(64 + j) * 256]);
  ((u16x8*)w1ot)[tid] = v;
}

// ---- P4: Wp^T -------------------------------------------------------------
__global__ void prep_wp_k(const float* __restrict__ Wp, unsigned short* __restrict__ wpt) {
  const int tid = blockIdx.x * 256 + threadIdx.x;   // 32768
  const int k8 = tid & 31, a = (tid >> 5) & 15, s = tid >> 9;
  const float* w = Wp + (size_t)s * 4096;           // [k][a]
  u16x8 v;
#pragma unroll
  for (int i = 0; i < 8; ++i) v[i] = f2bf(w[(k8 * 8 + i) * 16 + a]);
  ((u16x8*)wpt)[(s * 16 + a) * 32 + k8] = v;
}

// ---- main fused kernel ----------------------------------------------------
__global__ __launch_bounds__(512, 2) void actor_main(
    const float* __restrict__ x, const int* __restrict__ midx,
    const float* __restrict__ c1ws, const unsigned short* __restrict__ w1ot,
    const float* __restrict__ g1, const float* __restrict__ be1,
    const unsigned short* __restrict__ w2t,
    const float* __restrict__ b2, const float* __restrict__ g2, const float* __restrict__ be2,
    const unsigned short* __restrict__ wpt, const float* __restrict__ bp,
    float* __restrict__ out) {
  extern __shared__ char lds[];               // [0,131072) W2^T, [131072,163840) act
  char*   ldsA = lds + 131072;
  float2* ldsP = (float2*)(lds + 131072);     // LN partials alias act rows 0..3

  const int tid = threadIdx.x;
  const int w = tid >> 6, l = tid & 63, lg = l & 15, g = l >> 4;
  const int p = w & 1, q = w >> 1;            // bt-pair, nt-quad
  const int s = blockIdx.x >> 2;
  const int rowstart = (blockIdx.x & 3) * 4096;
  const int swz = (lg & 7) << 4;

  { // stage W2^T blob (linear; swizzle pre-baked)
    const u32x4* src = (const u32x4*)(w2t + (size_t)s * 65536);
#pragma unroll
    for (int i = 0; i < 16; ++i)
      *(u32x4*)(lds + i * 8192 + tid * 16) = src[i * 512 + tid];
  }

  int mi[8];
#pragma unroll
  for (int j = 0; j < 8; ++j) mi[j] = midx[s * 8 + j];

  f32x4 c1v[4], b2v[4];
#pragma unroll
  for (int i = 0; i < 4; ++i) {
    const int n0 = (4 * q + i) * 16 + g * 4;
    c1v[i] = *(const f32x4*)(c1ws + s * 256 + n0);
    b2v[i] = *(const f32x4*)(b2 + s * 256 + n0);
  }
  const f32x4 bpv = *(const f32x4*)(bp + s * 16 + g * 4);

  bf16x8 a1[4];
#pragma unroll
  for (int i = 0; i < 4; ++i) {
    bf16x8 z = {0, 0, 0, 0, 0, 0, 0, 0};
    if (g == 0) z = *(const bf16x8*)(w1ot + ((size_t)s * 256 + (4 * q + i) * 16 + lg) * 8);
    a1[i] = z;
  }
  __syncthreads();   // staging complete

  for (int ch = 0; ch < 64; ++ch) {
    const int rowbase = rowstart + ch * 64;

    // ---- layer 1: D1[n][b] = W1o^T x o^T  (A,B real only in lanes g==0) ---
    bf16x8 bo[2];
#pragma unroll
    for (int j = 0; j < 2; ++j) {
      bf16x8 z = {0, 0, 0, 0, 0, 0, 0, 0};
      if (g == 0) {
        const float* xr = x + (size_t)(rowbase + p * 32 + j * 16 + lg) * 64;
#pragma unroll
        for (int jj = 0; jj < 8; ++jj) {
          const int m = mi[jj];
          const float v = xr[m < 0 ? 0 : m];
          z[jj] = (short)f2bf(m < 0 ? 0.0f : v);
        }
      }
      bo[j] = z;
    }
    f32x4 acc[4][2];
#pragma unroll
    for (int i = 0; i < 4; ++i)
#pragma unroll
      for (int j = 0; j < 2; ++j) acc[i][j] = c1v[i];
#pragma unroll
    for (int i = 0; i < 4; ++i)
#pragma unroll
      for (int j = 0; j < 2; ++j) acc[i][j] = MFMA16(a1[i], bo[j], acc[i][j]);

    // ---- LeakyReLU + LN1 --------------------------------------------------
    float sum[2] = {0.f, 0.f}, ssq[2] = {0.f, 0.f};
#pragma unroll
    for (int i = 0; i < 4; ++i)
#pragma unroll
      for (int j = 0; j < 2; ++j)
#pragma unroll
        for (int r = 0; r < 4; ++r) {
          float v = acc[i][j][r];
          v = (v < 0.f) ? v * NEGS : v;
          acc[i][j][r] = v;
          sum[j] += v; ssq[j] += v * v;
        }
#pragma unroll
    for (int j = 0; j < 2; ++j) {
      sum[j] += __shfl_xor(sum[j], 16, 64); sum[j] += __shfl_xor(sum[j], 32, 64);
      ssq[j] += __shfl_xor(ssq[j], 16, 64); ssq[j] += __shfl_xor(ssq[j], 32, 64);
    }
    __syncthreads();                                   // A: prev L3 done w/ ldsA
    if (l < 16) {
#pragma unroll
      for (int j = 0; j < 2; ++j)
        ldsP[(p * 32 + j * 16 + l) * 4 + q] = make_float2(sum[j], ssq[j]);
    }
    __syncthreads();                                   // B
    float mean[2], rstd[2];
#pragma unroll
    for (int j = 0; j < 2; ++j) {
      const int b = p * 32 + j * 16 + lg;
      f32x4 u0 = *(const f32x4*)(ldsP + b * 4);
      f32x4 u1 = *(const f32x4*)(ldsP + b * 4 + 2);
      const float sm = u0[0] + u0[2] + u1[0] + u1[2];
      const float sq = u0[1] + u0[3] + u1[1] + u1[3];
      mean[j] = sm * (1.f / 256.f);
      const float var = sq * (1.f / 256.f) - mean[j] * mean[j];
      rstd[j] = rsqrtf(var + LNEPS);
    }
    __syncthreads();                                   // C: partial reads done
#pragma unroll
    for (int i = 0; i < 4; ++i) {
      const int n0 = (4 * q + i) * 16 + g * 4;
      const f32x4 gv = *(const f32x4*)(g1 + s * 256 + n0);
      const f32x4 bv = *(const f32x4*)(be1 + s * 256 + n0);
#pragma unroll
      for (int j = 0; j < 2; ++j) {
        const int b = p * 32 + j * 16 + lg;
        u16x4 ov;
#pragma unroll
        for (int r = 0; r < 4; ++r)
          ov[r] = f2bf((acc[i][j][r] - mean[j]) * rstd[j] * gv[r] + bv[r]);
        *(u16x4*)(ldsA + b * 512 + (((4 * q + i) * 32 + g * 8) ^ ((b & 7) << 4))) = ov;
      }
    }
    __syncthreads();                                   // D: h1n ready

    // ---- layer 2: D2[n][b] = W2^T x h1n^T ---------------------------------
    f32x4 acc2[4][2];
#pragma unroll
    for (int i = 0; i < 4; ++i)
#pragma unroll
      for (int j = 0; j < 2; ++j) acc2[i][j] = b2v[i];
#pragma unroll
    for (int t = 0; t < 8; ++t) {
      const int ko = t * 64 + g * 16;
      bf16x8 af[4], bfr[2];
#pragma unroll
      for (int i = 0; i < 4; ++i)
        af[i] = *(const bf16x8*)(lds + ((4 * q + i) * 16 + lg) * 512 + (ko ^ swz));
#pragma unroll
      for (int j = 0; j < 2; ++j)
        bfr[j] = *(const bf16x8*)(ldsA + (p * 32 + j * 16 + lg) * 512 + (ko ^ swz));
#pragma unroll
      for (int i = 0; i < 4; ++i)
#pragma unroll
        for (int j = 0; j < 2; ++j) acc2[i][j] = MFMA16(af[i], bfr[j], acc2[i][j]);
    }

    // ---- LeakyReLU + LN2 --------------------------------------------------
    float sum2[2] = {0.f, 0.f}, ssq2[2] = {0.f, 0.f};
#pragma unroll
    for (int i = 0; i < 4; ++i)
#pragma unroll
      for (int j = 0; j < 2; ++j)
#pragma unroll
        for (int r = 0; r < 4; ++r) {
          float v = acc2[i][j][r];
          v = (v < 0.f) ? v * NEGS : v;
          acc2[i][j][r] = v;
          sum2[j] += v; ssq2[j] += v * v;
        }
#pragma unroll
    for (int j = 0; j < 2; ++j) {
      sum2[j] += __shfl_xor(sum2[j], 16, 64); sum2[j] += __shfl_xor(sum2[j], 32, 64);
      ssq2[j] += __shfl_xor(ssq2[j], 16, 64); ssq2[j] += __shfl_xor(ssq2[j], 32, 64);
    }
    __syncthreads();                                   // E: L2 reads of ldsA done
    if (l < 16) {
#pragma unroll
      for (int j = 0; j < 2; ++j)
        ldsP[(p * 32 + j * 16 + l) * 4 + q] = make_float2(sum2[j], ssq2[j]);
    }
    __syncthreads();                                   // F
#pragma unroll
    for (int j = 0; j < 2; ++j) {
      const int b = p * 32 + j * 16 + lg;
      f32x4 u0 = *(const f32x4*)(ldsP + b * 4);
      f32x4 u1 = *(const f32x4*)(ldsP + b * 4 + 2);
      const float sm = u0[0] + u0[2] + u1[0] + u1[2];
      const float sq = u0[1] + u0[3] + u1[1] + u1[3];
      mean[j] = sm * (1.f / 256.f);
      const float var = sq * (1.f / 256.f) - mean[j] * mean[j];
      rstd[j] = rsqrtf(var + LNEPS);
    }
    __syncthreads();                                   // G
#pragma unroll
    for (int i = 0; i < 4; ++i) {
      const int n0 = (4 * q + i) * 16 + g * 4;
      const f32x4 gv = *(const f32x4*)(g2 + s * 256 + n0);
      const f32x4 bv = *(const f32x4*)(be2 + s * 256 + n0);
#pragma unroll
      for (int j = 0; j < 2; ++j) {
        const int b = p * 32 + j * 16 + lg;
        u16x4 ov;
#pragma unroll
        for (int r = 0; r < 4; ++r)
          ov[r] = f2bf((acc2[i][j][r] - mean[j]) * rstd[j] * gv[r] + bv[r]);
        *(u16x4*)(ldsA + b * 512 + (((4 * q + i) * 32 + g * 8) ^ ((b & 7) << 4))) = ov;
      }
    }
    __syncthreads();                                   // H: h2n ready

    // ---- layer 3 + log-softmax (waves 0..3, one 16-row b-tile each) -------
    if (w < 4) {
      f32x4 acc3 = bpv;
#pragma unroll
      for (int t = 0; t < 8; ++t) {
        const bf16x8 wf = *(const bf16x8*)(wpt + (size_t)s * 4096 + lg * 256 + g * 8 + t * 32);
        const bf16x8 hb = *(const bf16x8*)(ldsA + (w * 16 + lg) * 512 + ((t * 64 + g * 16) ^ swz));
        acc3 = MFMA16(wf, hb, acc3);
      }
      float mx = fmaxf(fmaxf(acc3[0], acc3[1]), fmaxf(acc3[2], acc3[3]));
      mx = fmaxf(mx, __shfl_xor(mx, 16, 64));
      mx = fmaxf(mx, __shfl_xor(mx, 32, 64));
      float es = __expf(acc3[0] - mx) + __expf(acc3[1] - mx) +
                 __expf(acc3[2] - mx) + __expf(acc3[3] - mx);
      es += __shfl_xor(es, 16, 64);
      es += __shfl_xor(es, 32, 64);
      const float lse = mx + __logf(es);
      const size_t ob = ((size_t)(rowbase + w * 16 + lg) * 64 + s) * 16 + g * 4;
      *(f32x4*)(out + ob) = acc3;
      f32x4 lsv = acc3 - lse;
      *(f32x4*)(out + 16777216 + ob) = lsv;
    }
  }
}

extern "C" void kernel_launch(void* const* d_in, const int* in_sizes, int n_in,
                              void* d_out, int out_size, void* d_ws, size_t ws_size,
                              hipStream_t stream) {
  const float* x    = (const float*)d_in[0];
  const int*   oidx = (const int*)d_in[1];
  const unsigned* omask = (const unsigned*)d_in[2];
  const float* W1 = (const float*)d_in[3];
  const float* b1 = (const float*)d_in[4];
  const float* g1 = (const float*)d_in[5];
  const float* be1 = (const float*)d_in[6];
  const float* W2 = (const float*)d_in[7];
  const float* b2 = (const float*)d_in[8];
  const float* g2 = (const float*)d_in[9];
  const float* be2 = (const float*)d_in[10];
  const float* Wp = (const float*)d_in[11];
  const float* bp = (const float*)d_in[12];
  float* out = (float*)d_out;

  char* ws = (char*)d_ws;
  unsigned*        wsW2T  = (unsigned*)(ws + WS_W2T);
  unsigned short*  wsW1OT = (unsigned short*)(ws + WS_W1OT);
  float*           wsC1   = (float*)(ws + WS_C1);
  unsigned short*  wsWPT  = (unsigned short*)(ws + WS_WPT);
  int*             wsMIDX = (int*)(ws + WS_MIDX);

  prep_midx_k<<<1, 512, 0, stream>>>(oidx, omask, wsMIDX);
  prep_w2t_k<<<8192, 256, 0, stream>>>(W2, wsW2T);
  prep_w1_k<<<64, 256, 0, stream>>>(W1, b1, wsW1OT, wsC1);
  prep_wp_k<<<128, 256, 0, stream>>>(Wp, wsWPT);

  hipFuncSetAttribute((const void*)actor_main,
                      hipFuncAttributeMaxDynamicSharedMemorySize, 163840);
  actor_main<<<256, 512, 163840, stream>>>(
      x, wsMIDX, wsC1, wsW1OT, g1, be1,
      (const unsigned short*)wsW2T, b2, g2, be2, wsWPT, bp, out);
}

// Round 2
// 327.949 us; speedup vs baseline: 1.4429x; 1.4429x over previous
//
#include <hip/hip_runtime.h>

#define LNEPS 1e-5f

typedef __attribute__((ext_vector_type(8)))  short          bf16x8;
typedef __attribute__((ext_vector_type(8)))  unsigned short u16x8;
typedef __attribute__((ext_vector_type(4)))  float          f32x4;
typedef __attribute__((ext_vector_type(16))) float          f32x16;
typedef __attribute__((ext_vector_type(4)))  unsigned int   u32x4;

#define MFMA32(a, b, c) __builtin_amdgcn_mfma_f32_32x32x16_bf16((a), (b), (c), 0, 0, 0)

// workspace byte offsets (~10.1 MB)
#define WS_W2G  0          // 64 * 128KB  : W2*g1 ^T blob [s][i][t][lane] bf16x8
#define WS_A1   8388608    // 64*8*64*16B : layer-1 A-frags (W1o^T | c1)
#define WS_WPG  8912896    // 64*17*64*16B: layer-3 A-frags (Wp*g2 ^T | up,cp)
#define WS_UC2  10027008   // 64*256*4B   : packed bf16 (u[n], c2[n])
#define WS_MIDX 10092544   // 512*4B      : masked neighbor idx (-1 = masked)

union U8 { bf16x8 v; unsigned u[4]; };

__device__ __forceinline__ unsigned short f2bf(float v) {
  union { float f; unsigned u; } a; a.f = v;
  unsigned r = a.u + 0x7fffu + ((a.u >> 16) & 1u);   // RTNE
  return (unsigned short)(r >> 16);
}
__device__ __forceinline__ unsigned cvtpk(float lo, float hi) {
  unsigned r;
  asm("v_cvt_pk_bf16_f32 %0, %1, %2" : "=v"(r) : "v"(lo), "v"(hi));
  return r;
}
// After: lo = (low-32-lane values everywhere), hi = (high-32-lane values everywhere)
__device__ __forceinline__ void plswap(unsigned w, unsigned& lo, unsigned& hi) {
  unsigned a = w, b = w;
  asm volatile("v_permlane32_swap_b32 %0, %1" : "+v"(a), "+v"(b));
  lo = a; hi = b;
}

// ---- P1: mask format detect + masked index table (unchanged, verified) ----
__global__ void prep_midx_k(const int* __restrict__ oidx,
                            const unsigned* __restrict__ mask32,
                            int* __restrict__ midx) {
  __shared__ int fgt1, ffl;
  const int t = threadIdx.x;            // 512 threads
  if (t == 0) { fgt1 = 0; ffl = 0; }
  __syncthreads();
  if (t < 128) {
    unsigned wv = mask32[t];
    if (wv == 0x3f800000u) atomicOr(&ffl, 1);
    else if (wv > 1u)      atomicOr(&fgt1, 1);
  }
  __syncthreads();
  const int mode = ffl ? 2 : (fgt1 ? 1 : 0);
  int mv;
  if (mode == 2)      mv = (((const float*)mask32)[t] != 0.0f) ? 1 : 0;
  else if (mode == 1) mv = (int)((const unsigned char*)mask32)[t];
  else                mv = ((const int*)mask32)[t];
  midx[t] = (mv != 0) ? oidx[t] : -1;
}

// ---- P2: W2*g1 -> bf16 A-frag blob [s][i][t][lane] ------------------------
__global__ __launch_bounds__(256) void prep_w2g_k(
    const float* __restrict__ W2, const float* __restrict__ g1,
    unsigned short* __restrict__ w2g) {
  const int tid = blockIdx.x * 256 + threadIdx.x;   // 524288
  const int l = tid & 63;
  const int t = (tid >> 6) & 15;
  const int i = (tid >> 10) & 7;
  const int s = tid >> 13;
  const int n = i * 32 + (l & 31);
  const int h = l >> 5;
  const float* w = W2 + (size_t)s * 65536;          // [k][n]
  const float* g = g1 + s * 256;
  u16x8 v;
#pragma unroll
  for (int j = 0; j < 8; ++j) {
    const int k = t * 16 + h * 8 + j;
    v[j] = f2bf(w[k * 256 + n] * g[k]);
  }
  ((u16x8*)w2g)[tid] = v;
}

// ---- P3: u[n] = sum_k W2*g1, c2[n] = sum_k W2*be1 + b2, packed bf16 -------
__global__ __launch_bounds__(256) void prep_uc2_k(
    const float* __restrict__ W2, const float* __restrict__ g1,
    const float* __restrict__ be1, const float* __restrict__ b2,
    unsigned* __restrict__ uc2) {
  const int tid = blockIdx.x * 256 + threadIdx.x;   // 16384
  const int s = tid >> 8, n = tid & 255;
  const float* w = W2 + (size_t)s * 65536 + n;
  const float* g = g1 + s * 256;
  const float* be = be1 + s * 256;
  float u = 0.f, c = 0.f;
#pragma unroll 8
  for (int k = 0; k < 256; ++k) {
    const float wk = w[k * 256];
    u = fmaf(wk, g[k], u);
    c = fmaf(wk, be[k], c);
  }
  c += b2[tid];
  uc2[tid] = (unsigned)f2bf(u) | ((unsigned)f2bf(c) << 16);
}

// ---- P4: layer-1 A-frags [s][i][lane]: lanes<32 = W1o^T, lanes>=32 = c1 ---
__global__ __launch_bounds__(256) void prep_a1_k(
    const float* __restrict__ W1, const float* __restrict__ b1,
    unsigned short* __restrict__ a1b) {
  const int tid = blockIdx.x * 256 + threadIdx.x;   // 32768
  const int l = tid & 63;
  const int i = (tid >> 6) & 7;
  const int s = tid >> 9;
  const int n = i * 32 + (l & 31);
  const float* w = W1 + (size_t)s * 72 * 256;
  u16x8 v;
#pragma unroll
  for (int j = 0; j < 8; ++j) v[j] = 0;
  if (l < 32) {
#pragma unroll
    for (int j = 0; j < 8; ++j) v[j] = f2bf(w[(64 + j) * 256 + n]);
  } else {
    v[0] = f2bf(w[s * 256 + n] + b1[s * 256 + n]);  // c1, rides k=8 (ones slot)
  }
  ((u16x8*)a1b)[tid] = v;
}

// ---- P5: layer-3 A-frags [s][t0..16][lane] (Wp*g2 ^T, ext = up,cp) --------
__global__ __launch_bounds__(256) void prep_wpg_k(
    const float* __restrict__ Wp, const float* __restrict__ g2,
    const float* __restrict__ be2, const float* __restrict__ bp,
    unsigned short* __restrict__ wpg) {
  const int tid = blockIdx.x * 256 + threadIdx.x;   // 69632
  const int l = tid & 63;
  const int r = tid >> 6;
  const int t = r % 17;
  const int s = r / 17;
  const int a = l & 31;
  const int h = l >> 5;
  u16x8 v;
#pragma unroll
  for (int j = 0; j < 8; ++j) v[j] = 0;
  if (t < 16) {
    if (a < 16) {
      const float* w = Wp + (size_t)s * 4096;       // [k][a]
      const float* g = g2 + s * 256;
#pragma unroll
      for (int j = 0; j < 8; ++j) {
        const int k = t * 16 + h * 8 + j;
        v[j] = f2bf(w[k * 16 + a] * g[k]);
      }
    }
  } else if (h == 0 && a < 16) {
    const float* w = Wp + (size_t)s * 4096;
    float up = 0.f, cp = 0.f;
#pragma unroll 8
    for (int k = 0; k < 256; ++k) {
      const float wk = w[k * 16 + a];
      up = fmaf(wk, g2[s * 256 + k], up);
      cp = fmaf(wk, be2[s * 256 + k], cp);
    }
    cp += bp[s * 16 + a];
    v[0] = f2bf(up); v[1] = f2bf(cp);
  }
  ((u16x8*)wpg)[tid] = v;
}

// ---- in-register C-layout -> B-frag conversion (one 32-wide n-tile) -------
__device__ __forceinline__ void pack_tile(const f32x16& a, const int h,
                                          unsigned* f0, unsigned* f1) {
  unsigned lo[8], hi[8];
#pragma unroll
  for (int m = 0; m < 8; ++m) {
    unsigned w = cvtpk(a[2 * m], a[2 * m + 1]);
    plswap(w, lo[m], hi[m]);
  }
  f0[0] = h ? lo[2] : lo[0];
  f0[1] = h ? lo[3] : lo[1];
  f0[2] = h ? hi[2] : hi[0];
  f0[3] = h ? hi[3] : hi[1];
  f1[0] = h ? lo[6] : lo[4];
  f1[1] = h ? lo[7] : lo[5];
  f1[2] = h ? hi[6] : hi[4];
  f1[3] = h ? hi[7] : hi[5];
}

// ---- main fused kernel: barrier-free after staging ------------------------
__global__ __launch_bounds__(512, 2) void actor_main(
    const float* __restrict__ x, const int* __restrict__ midx,
    const unsigned short* __restrict__ w2g, const unsigned* __restrict__ uc2,
    const unsigned short* __restrict__ a1b, const unsigned short* __restrict__ wpg,
    float* __restrict__ out) {
  extern __shared__ char lds[];                 // 128KB W2g blob
  const int tid = threadIdx.x;
  const int wv = tid >> 6;
  const int l = tid & 63;
  const int bl = l & 31;
  const int h = l >> 5;
  const int s = blockIdx.x >> 2;
  const int rowstart = (blockIdx.x & 3) << 12;

  { // stage W2g blob, linear, conflict-free
    const u32x4* src = (const u32x4*)(w2g + (size_t)s * 65536);
    u32x4* dst = (u32x4*)lds;
#pragma unroll
    for (int i = 0; i < 16; ++i) dst[i * 512 + tid] = src[i * 512 + tid];
  }

  unsigned aext[8];
#pragma unroll
  for (int i = 0; i < 8; ++i) {
    const unsigned t = uc2[(s * 8 + i) * 32 + bl];
    aext[i] = h ? 0u : t;
  }
  const int4 mi4 = ((const int4*)(midx + s * 8))[h];
  const bf16x8* A1 = ((const bf16x8*)a1b) + (size_t)(s * 8) * 64 + l;
  const bf16x8* A3 = ((const bf16x8*)wpg) + (size_t)(s * 17) * 64 + l;

  __syncthreads();   // only barrier: W2g staged

  for (int it = 0; it < 16; ++it) {
    const int row = rowstart + it * 256 + wv * 32 + bl;

    // ---- layer 1: D1[n][b], K=16 (8 features + ones-slot carrying c1) ----
    const float* xr = x + (size_t)row * 64;
    const float ga = mi4.x < 0 ? 0.f : xr[mi4.x];
    const float gb = mi4.y < 0 ? 0.f : xr[mi4.y];
    const float gc = mi4.z < 0 ? 0.f : xr[mi4.z];
    const float gd = mi4.w < 0 ? 0.f : xr[mi4.w];
    unsigned oa0, ob0, oa1, ob1;
    plswap(cvtpk(ga, gb), oa0, ob0);
    plswap(cvtpk(gc, gd), oa1, ob1);
    U8 B1;
    B1.u[0] = h ? 0x00003F80u : oa0;   // h=1: k=8 -> 1.0 (c1 slot)
    B1.u[1] = h ? 0u : oa1;
    B1.u[2] = h ? 0u : ob0;
    B1.u[3] = h ? 0u : ob1;
    f32x16 acc1[8];
#pragma unroll
    for (int i = 0; i < 8; ++i) {
      f32x16 z = {};
      acc1[i] = MFMA32(A1[i * 64], B1.v, z);
    }

    // ---- leaky + in-wave LN1 stats -----------------------------------
    float s0 = 0.f, s1 = 0.f, q0 = 0.f, q1 = 0.f;
#pragma unroll
    for (int i = 0; i < 8; ++i)
#pragma unroll
      for (int r = 0; r < 16; ++r) {
        float v = acc1[i][r];
        v = fmaxf(v, 0.01f * v);
        acc1[i][r] = v;
        if (r & 1) { s1 += v; q1 = fmaf(v, v, q1); }
        else       { s0 += v; q0 = fmaf(v, v, q0); }
      }
    float sum = s0 + s1, ssq = q0 + q1;
    sum += __shfl_xor(sum, 32, 64);
    ssq += __shfl_xor(ssq, 32, 64);
    const float m1 = sum * 0.00390625f;
    const float var1 = fmaf(ssq, 0.00390625f, -m1 * m1) + LNEPS;
    const float rho1 = rsqrtf(var1);
    const float std1 = var1 * rho1;               // = 1/rho1
    const unsigned be2w = cvtpk(-m1, std1);

    unsigned yf[16][4];
#pragma unroll
    for (int i = 0; i < 8; ++i) pack_tile(acc1[i], h, yf[2 * i], yf[2 * i + 1]);

    // ---- layer 2: acc2[n][b] = W2g^T y1 (+ LN correction k-step) ------
    f32x16 acc2[8];
#pragma unroll
    for (int i = 0; i < 8; ++i) { f32x16 z = {}; acc2[i] = z; }
#pragma unroll
    for (int t = 0; t < 16; ++t) {
      U8 Bf;
      Bf.u[0] = yf[t][0]; Bf.u[1] = yf[t][1]; Bf.u[2] = yf[t][2]; Bf.u[3] = yf[t][3];
#pragma unroll
      for (int i = 0; i < 8; ++i) {
        const bf16x8 Af = *(const bf16x8*)(lds + (((i << 4) + t) << 10) + (l << 4));
        acc2[i] = MFMA32(Af, Bf.v, acc2[i]);
      }
    }
    {
      U8 Bx; Bx.u[0] = h ? 0u : be2w; Bx.u[1] = 0; Bx.u[2] = 0; Bx.u[3] = 0;
#pragma unroll
      for (int i = 0; i < 8; ++i) {
        U8 Ax; Ax.u[0] = aext[i]; Ax.u[1] = 0; Ax.u[2] = 0; Ax.u[3] = 0;
        acc2[i] = MFMA32(Ax.v, Bx.v, acc2[i]);
      }
    }

    // ---- leaky + LN2 stats (deferred rho1 scaling) ---------------------
    s0 = s1 = q0 = q1 = 0.f;
#pragma unroll
    for (int i = 0; i < 8; ++i)
#pragma unroll
      for (int r = 0; r < 16; ++r) {
        float v = acc2[i][r];
        v = fmaxf(v, 0.01f * v);
        acc2[i][r] = v;
        if (r & 1) { s1 += v; q1 = fmaf(v, v, q1); }
        else       { s0 += v; q0 = fmaf(v, v, q0); }
      }
    float sum2 = s0 + s1, ssq2 = q0 + q1;
    sum2 += __shfl_xor(sum2, 32, 64);
    ssq2 += __shfl_xor(ssq2, 32, 64);
    const float mp = sum2 * 0.00390625f;
    const float qp = ssq2 * 0.00390625f;
    const float var2 = rho1 * rho1 * fmaf(-mp, mp, qp) + LNEPS;
    const float rho2 = rsqrtf(var2);
    const float sigma = rho1 * rho2;
    const float inv = var2 * rho2 * std1;         // = 1/sigma
    const unsigned be3w = cvtpk(-mp, inv);

#pragma unroll
    for (int i = 0; i < 8; ++i) pack_tile(acc2[i], h, yf[2 * i], yf[2 * i + 1]);

    // ---- layer 3 + log-softmax ----------------------------------------
    f32x16 a3a = {}, a3b = {};
#pragma unroll
    for (int t = 0; t < 16; t += 2) {
      U8 B0, Bq;
      B0.u[0] = yf[t][0]; B0.u[1] = yf[t][1]; B0.u[2] = yf[t][2]; B0.u[3] = yf[t][3];
      Bq.u[0] = yf[t + 1][0]; Bq.u[1] = yf[t + 1][1]; Bq.u[2] = yf[t + 1][2]; Bq.u[3] = yf[t + 1][3];
      a3a = MFMA32(A3[t * 64], B0.v, a3a);
      a3b = MFMA32(A3[(t + 1) * 64], Bq.v, a3b);
    }
    {
      U8 Bx; Bx.u[0] = h ? 0u : be3w; Bx.u[1] = 0; Bx.u[2] = 0; Bx.u[3] = 0;
      a3a = MFMA32(A3[16 * 64], Bx.v, a3a);
    }
    float lg[8];
#pragma unroll
    for (int r = 0; r < 8; ++r) lg[r] = sigma * (a3a[r] + a3b[r]);
    float mx = fmaxf(fmaxf(fmaxf(lg[0], lg[1]), fmaxf(lg[2], lg[3])),
                     fmaxf(fmaxf(lg[4], lg[5]), fmaxf(lg[6], lg[7])));
    mx = fmaxf(mx, __shfl_xor(mx, 32, 64));
    float es = 0.f;
#pragma unroll
    for (int r = 0; r < 8; ++r) es += __expf(lg[r] - mx);
    es += __shfl_xor(es, 32, 64);
    const float lse = mx + __logf(es);

    const size_t ob = (((size_t)row << 6) + s) * 16 + (h << 2);
    f32x4 v0 = {lg[0], lg[1], lg[2], lg[3]};
    f32x4 v1 = {lg[4], lg[5], lg[6], lg[7]};
    *(f32x4*)(out + ob) = v0;
    *(f32x4*)(out + ob + 8) = v1;
    f32x4 w0 = {lg[0] - lse, lg[1] - lse, lg[2] - lse, lg[3] - lse};
    f32x4 w1 = {lg[4] - lse, lg[5] - lse, lg[6] - lse, lg[7] - lse};
    *(f32x4*)(out + 16777216 + ob) = w0;
    *(f32x4*)(out + 16777216 + ob + 8) = w1;
  }
}

extern "C" void kernel_launch(void* const* d_in, const int* in_sizes, int n_in,
                              void* d_out, int out_size, void* d_ws, size_t ws_size,
                              hipStream_t stream) {
  const float* x    = (const float*)d_in[0];
  const int*   oidx = (const int*)d_in[1];
  const unsigned* omask = (const unsigned*)d_in[2];
  const float* W1 = (const float*)d_in[3];
  const float* b1 = (const float*)d_in[4];
  const float* g1 = (const float*)d_in[5];
  const float* be1 = (const float*)d_in[6];
  const float* W2 = (const float*)d_in[7];
  const float* b2 = (const float*)d_in[8];
  const float* g2 = (const float*)d_in[9];
  const float* be2 = (const float*)d_in[10];
  const float* Wp = (const float*)d_in[11];
  const float* bp = (const float*)d_in[12];
  float* out = (float*)d_out;

  char* ws = (char*)d_ws;
  unsigned short* wsW2G = (unsigned short*)(ws + WS_W2G);
  unsigned short* wsA1  = (unsigned short*)(ws + WS_A1);
  unsigned short* wsWPG = (unsigned short*)(ws + WS_WPG);
  unsigned*       wsUC2 = (unsigned*)(ws + WS_UC2);
  int*            wsMIDX = (int*)(ws + WS_MIDX);

  prep_midx_k<<<1, 512, 0, stream>>>(oidx, omask, wsMIDX);
  prep_w2g_k<<<2048, 256, 0, stream>>>(W2, g1, wsW2G);
  prep_uc2_k<<<64, 256, 0, stream>>>(W2, g1, be1, b2, wsUC2);
  prep_a1_k<<<128, 256, 0, stream>>>(W1, b1, wsA1);
  prep_wpg_k<<<272, 256, 0, stream>>>(Wp, g2, be2, bp, wsWPG);

  hipFuncSetAttribute((const void*)actor_main,
                      hipFuncAttributeMaxDynamicSharedMemorySize, 131072);
  actor_main<<<256, 512, 131072, stream>>>(
      x, wsMIDX, wsW2G, wsUC2, wsA1, wsWPG, out);
}

// Round 3
// 321.840 us; speedup vs baseline: 1.4703x; 1.0190x over previous
//
#include <hip/hip_runtime.h>

#define LNEPS 1e-5f

typedef __attribute__((ext_vector_type(8)))  short          bf16x8;
typedef __attribute__((ext_vector_type(8)))  unsigned short u16x8;
typedef __attribute__((ext_vector_type(4)))  float          f32x4;
typedef __attribute__((ext_vector_type(16))) float          f32x16;
typedef __attribute__((ext_vector_type(4)))  unsigned int   u32x4;

#define MFMA32(a, b, c) __builtin_amdgcn_mfma_f32_32x32x16_bf16((a), (b), (c), 0, 0, 0)

// workspace byte offsets (~10.1 MB)
#define WS_W2G  0          // 64 * 128KB  : W2*g1 ^T blob [s][i][t][lane] bf16x8
#define WS_A1   8388608    // 64*8*64*16B : layer-1 A-frags (W1o^T | c1)
#define WS_WPG  8912896    // 64*17*64*16B: layer-3 A-frags (Wp*g2 ^T | up,cp)
#define WS_UC2  10027008   // 64*256*4B   : packed bf16 (u[n], c2[n])
#define WS_MIDX 10092544   // 512*4B      : masked neighbor idx (-1 = masked)

union U8 { bf16x8 v; unsigned u[4]; };

__device__ __forceinline__ unsigned short f2bf(float v) {
  union { float f; unsigned u; } a; a.f = v;
  unsigned r = a.u + 0x7fffu + ((a.u >> 16) & 1u);   // RTNE
  return (unsigned short)(r >> 16);
}
__device__ __forceinline__ unsigned cvtpk(float lo, float hi) {
  unsigned r;
  asm("v_cvt_pk_bf16_f32 %0, %1, %2" : "=v"(r) : "v"(lo), "v"(hi));
  return r;
}
// swaps a.hi31:0 lanes <-> b.lo lanes: a -> [a_lo | b_lo], b -> [a_hi | b_hi]
__device__ __forceinline__ void swap2(unsigned& a, unsigned& b) {
  asm volatile("v_permlane32_swap_b32 %0, %1" : "+v"(a), "+v"(b));
}
// legacy broadcast form: lo = [w_lo|w_lo], hi = [w_hi|w_hi]
__device__ __forceinline__ void plswap(unsigned w, unsigned& lo, unsigned& hi) {
  unsigned a = w, b = w;
  asm volatile("v_permlane32_swap_b32 %0, %1" : "+v"(a), "+v"(b));
  lo = a; hi = b;
}

// ---- P1: mask format detect + masked index table (verified) ---------------
__global__ void prep_midx_k(const int* __restrict__ oidx,
                            const unsigned* __restrict__ mask32,
                            int* __restrict__ midx) {
  __shared__ int fgt1, ffl;
  const int t = threadIdx.x;            // 512 threads
  if (t == 0) { fgt1 = 0; ffl = 0; }
  __syncthreads();
  if (t < 128) {
    unsigned wv = mask32[t];
    if (wv == 0x3f800000u) atomicOr(&ffl, 1);
    else if (wv > 1u)      atomicOr(&fgt1, 1);
  }
  __syncthreads();
  const int mode = ffl ? 2 : (fgt1 ? 1 : 0);
  int mv;
  if (mode == 2)      mv = (((const float*)mask32)[t] != 0.0f) ? 1 : 0;
  else if (mode == 1) mv = (int)((const unsigned char*)mask32)[t];
  else                mv = ((const int*)mask32)[t];
  midx[t] = (mv != 0) ? oidx[t] : -1;
}

// ---- P2: W2*g1 -> bf16 A-frag blob [s][i][t][lane] (verified) -------------
__global__ __launch_bounds__(256) void prep_w2g_k(
    const float* __restrict__ W2, const float* __restrict__ g1,
    unsigned short* __restrict__ w2g) {
  const int tid = blockIdx.x * 256 + threadIdx.x;   // 524288
  const int l = tid & 63;
  const int t = (tid >> 6) & 15;
  const int i = (tid >> 10) & 7;
  const int s = tid >> 13;
  const int n = i * 32 + (l & 31);
  const int h = l >> 5;
  const float* w = W2 + (size_t)s * 65536;          // [k][n]
  const float* g = g1 + s * 256;
  u16x8 v;
#pragma unroll
  for (int j = 0; j < 8; ++j) {
    const int k = t * 16 + h * 8 + j;
    v[j] = f2bf(w[k * 256 + n] * g[k]);
  }
  ((u16x8*)w2g)[tid] = v;
}

// ---- P3: u[n], c2[n] packed bf16 (verified) -------------------------------
__global__ __launch_bounds__(256) void prep_uc2_k(
    const float* __restrict__ W2, const float* __restrict__ g1,
    const float* __restrict__ be1, const float* __restrict__ b2,
    unsigned* __restrict__ uc2) {
  const int tid = blockIdx.x * 256 + threadIdx.x;   // 16384
  const int s = tid >> 8, n = tid & 255;
  const float* w = W2 + (size_t)s * 65536 + n;
  const float* g = g1 + s * 256;
  const float* be = be1 + s * 256;
  float u = 0.f, c = 0.f;
#pragma unroll 8
  for (int k = 0; k < 256; ++k) {
    const float wk = w[k * 256];
    u = fmaf(wk, g[k], u);
    c = fmaf(wk, be[k], c);
  }
  c += b2[tid];
  uc2[tid] = (unsigned)f2bf(u) | ((unsigned)f2bf(c) << 16);
}

// ---- P4: layer-1 A-frags (verified) ---------------------------------------
__global__ __launch_bounds__(256) void prep_a1_k(
    const float* __restrict__ W1, const float* __restrict__ b1,
    unsigned short* __restrict__ a1b) {
  const int tid = blockIdx.x * 256 + threadIdx.x;   // 32768
  const int l = tid & 63;
  const int i = (tid >> 6) & 7;
  const int s = tid >> 9;
  const int n = i * 32 + (l & 31);
  const float* w = W1 + (size_t)s * 72 * 256;
  u16x8 v;
#pragma unroll
  for (int j = 0; j < 8; ++j) v[j] = 0;
  if (l < 32) {
#pragma unroll
    for (int j = 0; j < 8; ++j) v[j] = f2bf(w[(64 + j) * 256 + n]);
  } else {
    v[0] = f2bf(w[s * 256 + n] + b1[s * 256 + n]);  // c1, rides k=8 (ones slot)
  }
  ((u16x8*)a1b)[tid] = v;
}

// ---- P5: layer-3 A-frags (verified) ---------------------------------------
__global__ __launch_bounds__(256) void prep_wpg_k(
    const float* __restrict__ Wp, const float* __restrict__ g2,
    const float* __restrict__ be2, const float* __restrict__ bp,
    unsigned short* __restrict__ wpg) {
  const int tid = blockIdx.x * 256 + threadIdx.x;   // 69632
  const int l = tid & 63;
  const int r = tid >> 6;
  const int t = r % 17;
  const int s = r / 17;
  const int a = l & 31;
  const int h = l >> 5;
  u16x8 v;
#pragma unroll
  for (int j = 0; j < 8; ++j) v[j] = 0;
  if (t < 16) {
    if (a < 16) {
      const float* w = Wp + (size_t)s * 4096;       // [k][a]
      const float* g = g2 + s * 256;
#pragma unroll
      for (int j = 0; j < 8; ++j) {
        const int k = t * 16 + h * 8 + j;
        v[j] = f2bf(w[k * 16 + a] * g[k]);
      }
    }
  } else if (h == 0 && a < 16) {
    const float* w = Wp + (size_t)s * 4096;
    float up = 0.f, cp = 0.f;
#pragma unroll 8
    for (int k = 0; k < 256; ++k) {
      const float wk = w[k * 16 + a];
      up = fmaf(wk, g2[s * 256 + k], up);
      cp = fmaf(wk, be2[s * 256 + k], cp);
    }
    cp += bp[s * 16 + a];
    v[0] = f2bf(up); v[1] = f2bf(cp);
  }
  ((u16x8*)wpg)[tid] = v;
}

// ---- pack one 32-n f32x16 acc tile -> two layer-2 B-frags (pair-swap) -----
__device__ __forceinline__ void pack_tile(const f32x16& a,
                                          unsigned* f0, unsigned* f1) {
  unsigned w0 = cvtpk(a[0], a[1]),   w1 = cvtpk(a[2], a[3]);
  unsigned w2 = cvtpk(a[4], a[5]),   w3 = cvtpk(a[6], a[7]);
  unsigned w4 = cvtpk(a[8], a[9]),   w5 = cvtpk(a[10], a[11]);
  unsigned w6 = cvtpk(a[12], a[13]), w7 = cvtpk(a[14], a[15]);
  swap2(w0, w2); swap2(w1, w3); swap2(w4, w6); swap2(w5, w7);
  f0[0] = w0; f0[1] = w1; f0[2] = w2; f0[3] = w3;
  f1[0] = w4; f1[1] = w5; f1[2] = w6; f1[3] = w7;
}

// ---- main fused kernel -----------------------------------------------------
__global__ __launch_bounds__(512, 2) void actor_main(
    const float* __restrict__ x, const int* __restrict__ midx,
    const unsigned short* __restrict__ w2g, const unsigned* __restrict__ uc2,
    const unsigned short* __restrict__ a1b, const unsigned short* __restrict__ wpg,
    float* __restrict__ out) {
  extern __shared__ char lds[];                 // 128KB W2g blob
  const int tid = threadIdx.x;
  const int wv = tid >> 6;
  const int l = tid & 63;
  const int bl = l & 31;
  const int h = l >> 5;
  const int s = blockIdx.x >> 2;
  const int rowstart = (blockIdx.x & 3) << 12;

  { // stage W2g blob, linear, conflict-free
    const u32x4* src = (const u32x4*)(w2g + (size_t)s * 65536);
    u32x4* dst = (u32x4*)lds;
#pragma unroll
    for (int i = 0; i < 16; ++i) dst[i * 512 + tid] = src[i * 512 + tid];
  }

  unsigned aext[8];
#pragma unroll
  for (int i = 0; i < 8; ++i) {
    const unsigned t = uc2[(s * 8 + i) * 32 + bl];
    aext[i] = h ? 0u : t;
  }
  const int4 mi4 = ((const int4*)(midx + s * 8))[h];
  const bf16x8* A1 = ((const bf16x8*)a1b) + (size_t)(s * 8) * 64 + l;
  const bf16x8* A3 = ((const bf16x8*)wpg) + (size_t)(s * 17) * 64 + l;

  const float* xbase = x + (size_t)(rowstart + wv * 32 + bl) * 64;

  // prologue gather (iter 0)
  float ga = mi4.x < 0 ? 0.f : xbase[mi4.x];
  float gb = mi4.y < 0 ? 0.f : xbase[mi4.y];
  float gc = mi4.z < 0 ? 0.f : xbase[mi4.z];
  float gd = mi4.w < 0 ? 0.f : xbase[mi4.w];

  __syncthreads();   // only barrier: W2g staged

  for (int it = 0; it < 16; ++it) {
    const int row = rowstart + it * 256 + wv * 32 + bl;

    // ---- build layer-1 B-frag from current gather ----------------------
    unsigned oa0, ob0, oa1, ob1;
    plswap(cvtpk(ga, gb), oa0, ob0);
    plswap(cvtpk(gc, gd), oa1, ob1);
    U8 B1;
    B1.u[0] = h ? 0x00003F80u : oa0;   // h=1: k=8 -> 1.0 (c1 slot)
    B1.u[1] = h ? 0u : oa1;
    B1.u[2] = h ? 0u : ob0;
    B1.u[3] = h ? 0u : ob1;

    // ---- prefetch next iteration's gather (index-wrap keeps in-bounds) --
    {
      const float* xn = xbase + (size_t)(((it + 1) & 15) * 256) * 64;
      ga = mi4.x < 0 ? 0.f : xn[mi4.x];
      gb = mi4.y < 0 ? 0.f : xn[mi4.y];
      gc = mi4.z < 0 ? 0.f : xn[mi4.z];
      gd = mi4.w < 0 ? 0.f : xn[mi4.w];
    }

    // ---- layer 1: D1[n][b], K=16 (8 features + ones-slot carrying c1) ---
    f32x16 acc1[8];
#pragma unroll
    for (int i = 0; i < 8; ++i) {
      f32x16 z = {};
      acc1[i] = MFMA32(A1[i * 64], B1.v, z);
    }

    // ---- leaky + in-wave LN1 stats + pack -------------------------------
    float s0 = 0.f, s1 = 0.f, q0 = 0.f, q1 = 0.f;
    unsigned yf[16][4];
#pragma unroll
    for (int i = 0; i < 8; ++i) {
#pragma unroll
      for (int r = 0; r < 16; ++r) {
        float v = acc1[i][r];
        v = fmaxf(v, 0.01f * v);
        acc1[i][r] = v;
        if (r & 1) { s1 += v; q1 = fmaf(v, v, q1); }
        else       { s0 += v; q0 = fmaf(v, v, q0); }
      }
      pack_tile(acc1[i], yf[2 * i], yf[2 * i + 1]);
    }
    float sum = s0 + s1, ssq = q0 + q1;
    sum += __shfl_xor(sum, 32, 64);
    ssq += __shfl_xor(ssq, 32, 64);
    const float m1 = sum * 0.00390625f;
    const float var1 = fmaf(ssq, 0.00390625f, -m1 * m1) + LNEPS;
    const float rho1 = rsqrtf(var1);
    const float std1 = var1 * rho1;               // = 1/rho1
    const unsigned be2w = cvtpk(-m1, std1);

    // ---- layer 2: acc2[n][b] = W2g^T y1 ---------------------------------
    f32x16 acc2[8];
#pragma unroll
    for (int i = 0; i < 8; ++i) { f32x16 z = {}; acc2[i] = z; }
#pragma unroll
    for (int t = 0; t < 16; ++t) {
      U8 Bf;
      Bf.u[0] = yf[t][0]; Bf.u[1] = yf[t][1]; Bf.u[2] = yf[t][2]; Bf.u[3] = yf[t][3];
      bf16x8 Af[8];
#pragma unroll
      for (int i = 0; i < 8; ++i)
        Af[i] = *(const bf16x8*)(lds + (((i << 4) + t) << 10) + (l << 4));
      __builtin_amdgcn_s_setprio(1);
#pragma unroll
      for (int i = 0; i < 8; ++i) acc2[i] = MFMA32(Af[i], Bf.v, acc2[i]);
      __builtin_amdgcn_s_setprio(0);
    }
    { // LN1 rank-1 correction k-step
      U8 Bx; Bx.u[0] = h ? 0u : be2w; Bx.u[1] = 0; Bx.u[2] = 0; Bx.u[3] = 0;
#pragma unroll
      for (int i = 0; i < 8; ++i) {
        U8 Ax; Ax.u[0] = aext[i]; Ax.u[1] = 0; Ax.u[2] = 0; Ax.u[3] = 0;
        acc2[i] = MFMA32(Ax.v, Bx.v, acc2[i]);
      }
    }

    // ---- leaky + LN2 stats + pack, with layer-3 MFMAs interleaved -------
    f32x16 a3a = {}, a3b = {};
    s0 = s1 = q0 = q1 = 0.f;
#pragma unroll
    for (int i = 0; i < 8; ++i) {
#pragma unroll
      for (int r = 0; r < 16; ++r) {
        float v = acc2[i][r];
        v = fmaxf(v, 0.01f * v);
        acc2[i][r] = v;
        if (r & 1) { s1 += v; q1 = fmaf(v, v, q1); }
        else       { s0 += v; q0 = fmaf(v, v, q0); }
      }
      U8 Bf0, Bf1;
      pack_tile(acc2[i], Bf0.u, Bf1.u);
      a3a = MFMA32(A3[(2 * i) * 64], Bf0.v, a3a);
      a3b = MFMA32(A3[(2 * i + 1) * 64], Bf1.v, a3b);
    }
    float sum2 = s0 + s1, ssq2 = q0 + q1;
    sum2 += __shfl_xor(sum2, 32, 64);
    ssq2 += __shfl_xor(ssq2, 32, 64);
    const float mp = sum2 * 0.00390625f;
    const float qp = ssq2 * 0.00390625f;
    const float var2 = rho1 * rho1 * fmaf(-mp, mp, qp) + LNEPS;
    const float rho2 = rsqrtf(var2);
    const float sigma = rho1 * rho2;
    const float inv = var2 * rho2 * std1;         // = 1/sigma
    const unsigned be3w = cvtpk(-mp, inv);
    { // LN2 rank-1 correction k-step
      U8 Bx; Bx.u[0] = h ? 0u : be3w; Bx.u[1] = 0; Bx.u[2] = 0; Bx.u[3] = 0;
      a3a = MFMA32(A3[16 * 64], Bx.v, a3a);
    }

    // ---- log-softmax + store --------------------------------------------
    float lg[8];
#pragma unroll
    for (int r = 0; r < 8; ++r) lg[r] = sigma * (a3a[r] + a3b[r]);
    float mx = fmaxf(fmaxf(fmaxf(lg[0], lg[1]), fmaxf(lg[2], lg[3])),
                     fmaxf(fmaxf(lg[4], lg[5]), fmaxf(lg[6], lg[7])));
    mx = fmaxf(mx, __shfl_xor(mx, 32, 64));
    float es = 0.f;
#pragma unroll
    for (int r = 0; r < 8; ++r) es += __expf(lg[r] - mx);
    es += __shfl_xor(es, 32, 64);
    const float lse = mx + __logf(es);

    const size_t ob = (((size_t)row << 6) + s) * 16 + (h << 2);
    f32x4 v0 = {lg[0], lg[1], lg[2], lg[3]};
    f32x4 v1 = {lg[4], lg[5], lg[6], lg[7]};
    *(f32x4*)(out + ob) = v0;
    *(f32x4*)(out + ob + 8) = v1;
    f32x4 w0 = {lg[0] - lse, lg[1] - lse, lg[2] - lse, lg[3] - lse};
    f32x4 w1 = {lg[4] - lse, lg[5] - lse, lg[6] - lse, lg[7] - lse};
    *(f32x4*)(out + 16777216 + ob) = w0;
    *(f32x4*)(out + 16777216 + ob + 8) = w1;
  }
}

extern "C" void kernel_launch(void* const* d_in, const int* in_sizes, int n_in,
                              void* d_out, int out_size, void* d_ws, size_t ws_size,
                              hipStream_t stream) {
  const float* x    = (const float*)d_in[0];
  const int*   oidx = (const int*)d_in[1];
  const unsigned* omask = (const unsigned*)d_in[2];
  const float* W1 = (const float*)d_in[3];
  const float* b1 = (const float*)d_in[4];
  const float* g1 = (const float*)d_in[5];
  const float* be1 = (const float*)d_in[6];
  const float* W2 = (const float*)d_in[7];
  const float* b2 = (const float*)d_in[8];
  const float* g2 = (const float*)d_in[9];
  const float* be2 = (const float*)d_in[10];
  const float* Wp = (const float*)d_in[11];
  const float* bp = (const float*)d_in[12];
  float* out = (float*)d_out;

  char* ws = (char*)d_ws;
  unsigned short* wsW2G = (unsigned short*)(ws + WS_W2G);
  unsigned short* wsA1  = (unsigned short*)(ws + WS_A1);
  unsigned short* wsWPG = (unsigned short*)(ws + WS_WPG);
  unsigned*       wsUC2 = (unsigned*)(ws + WS_UC2);
  int*            wsMIDX = (int*)(ws + WS_MIDX);

  prep_midx_k<<<1, 512, 0, stream>>>(oidx, omask, wsMIDX);
  prep_w2g_k<<<2048, 256, 0, stream>>>(W2, g1, wsW2G);
  prep_uc2_k<<<64, 256, 0, stream>>>(W2, g1, be1, b2, wsUC2);
  prep_a1_k<<<128, 256, 0, stream>>>(W1, b1, wsA1);
  prep_wpg_k<<<272, 256, 0, stream>>>(Wp, g2, be2, bp, wsWPG);

  hipFuncSetAttribute((const void*)actor_main,
                      hipFuncAttributeMaxDynamicSharedMemorySize, 131072);
  actor_main<<<256, 512, 131072, stream>>>(
      x, wsMIDX, wsW2G, wsUC2, wsA1, wsWPG, out);
}

// Round 4
// 272.289 us; speedup vs baseline: 1.7379x; 1.1820x over previous
//
#include <hip/hip_runtime.h>

#define LNEPS 1e-5f

typedef __attribute__((ext_vector_type(8)))  short          bf16x8;
typedef __attribute__((ext_vector_type(8)))  unsigned short u16x8;
typedef __attribute__((ext_vector_type(4)))  float          f32x4;
typedef __attribute__((ext_vector_type(16))) float          f32x16;
typedef __attribute__((ext_vector_type(4)))  unsigned int   u32x4;

#define MFMA32(a, b, c) __builtin_amdgcn_mfma_f32_32x32x16_bf16((a), (b), (c), 0, 0, 0)

// workspace byte offsets (~10.1 MB)
#define WS_W2G  0          // 64 * 128KB  : W2*g1 ^T blob [s][i][t][lane] bf16x8
#define WS_A1   8388608    // 64*8*64*16B : layer-1 A-frags (W1o^T | c1)
#define WS_WPG  8912896    // 64*17*64*16B: layer-3 A-frags (Wp*g2 ^T | up,cp)
#define WS_UC2  10027008   // 64*256*4B   : packed bf16 (u[n], c2[n])
#define WS_MIDX 10092544   // 512*4B      : masked neighbor idx (-1 = masked)

union U8 { bf16x8 v; unsigned u[4]; };

__device__ __forceinline__ unsigned short f2bf(float v) {
  union { float f; unsigned u; } a; a.f = v;
  unsigned r = a.u + 0x7fffu + ((a.u >> 16) & 1u);   // RTNE
  return (unsigned short)(r >> 16);
}
__device__ __forceinline__ unsigned cvtpk(float lo, float hi) {
  unsigned r;
  asm("v_cvt_pk_bf16_f32 %0, %1, %2" : "=v"(r) : "v"(lo), "v"(hi));
  return r;
}
// swaps: a -> [a_lo | b_lo], b -> [a_hi | b_hi]
__device__ __forceinline__ void swap2(unsigned& a, unsigned& b) {
  asm volatile("v_permlane32_swap_b32 %0, %1" : "+v"(a), "+v"(b));
}
// broadcast form: lo = [w_lo|w_lo], hi = [w_hi|w_hi]
__device__ __forceinline__ void plswap(unsigned w, unsigned& lo, unsigned& hi) {
  unsigned a = w, b = w;
  asm volatile("v_permlane32_swap_b32 %0, %1" : "+v"(a), "+v"(b));
  lo = a; hi = b;
}

// ---- P1: mask format detect + masked index table (verified) ---------------
__global__ void prep_midx_k(const int* __restrict__ oidx,
                            const unsigned* __restrict__ mask32,
                            int* __restrict__ midx) {
  __shared__ int fgt1, ffl;
  const int t = threadIdx.x;            // 512 threads
  if (t == 0) { fgt1 = 0; ffl = 0; }
  __syncthreads();
  if (t < 128) {
    unsigned wv = mask32[t];
    if (wv == 0x3f800000u) atomicOr(&ffl, 1);
    else if (wv > 1u)      atomicOr(&fgt1, 1);
  }
  __syncthreads();
  const int mode = ffl ? 2 : (fgt1 ? 1 : 0);
  int mv;
  if (mode == 2)      mv = (((const float*)mask32)[t] != 0.0f) ? 1 : 0;
  else if (mode == 1) mv = (int)((const unsigned char*)mask32)[t];
  else                mv = ((const int*)mask32)[t];
  midx[t] = (mv != 0) ? oidx[t] : -1;
}

// ---- P2: W2*g1 -> bf16 A-frag blob [s][i][t][lane] (verified) -------------
__global__ __launch_bounds__(256) void prep_w2g_k(
    const float* __restrict__ W2, const float* __restrict__ g1,
    unsigned short* __restrict__ w2g) {
  const int tid = blockIdx.x * 256 + threadIdx.x;   // 524288
  const int l = tid & 63;
  const int t = (tid >> 6) & 15;
  const int i = (tid >> 10) & 7;
  const int s = tid >> 13;
  const int n = i * 32 + (l & 31);
  const int h = l >> 5;
  const float* w = W2 + (size_t)s * 65536;          // [k][n]
  const float* g = g1 + s * 256;
  u16x8 v;
#pragma unroll
  for (int j = 0; j < 8; ++j) {
    const int k = t * 16 + h * 8 + j;
    v[j] = f2bf(w[k * 256 + n] * g[k]);
  }
  ((u16x8*)w2g)[tid] = v;
}

// ---- P3: u[n], c2[n] packed bf16 (verified) -------------------------------
__global__ __launch_bounds__(256) void prep_uc2_k(
    const float* __restrict__ W2, const float* __restrict__ g1,
    const float* __restrict__ be1, const float* __restrict__ b2,
    unsigned* __restrict__ uc2) {
  const int tid = blockIdx.x * 256 + threadIdx.x;   // 16384
  const int s = tid >> 8, n = tid & 255;
  const float* w = W2 + (size_t)s * 65536 + n;
  const float* g = g1 + s * 256;
  const float* be = be1 + s * 256;
  float u = 0.f, c = 0.f;
#pragma unroll 8
  for (int k = 0; k < 256; ++k) {
    const float wk = w[k * 256];
    u = fmaf(wk, g[k], u);
    c = fmaf(wk, be[k], c);
  }
  c += b2[tid];
  uc2[tid] = (unsigned)f2bf(u) | ((unsigned)f2bf(c) << 16);
}

// ---- P4: layer-1 A-frags (verified) ---------------------------------------
__global__ __launch_bounds__(256) void prep_a1_k(
    const float* __restrict__ W1, const float* __restrict__ b1,
    unsigned short* __restrict__ a1b) {
  const int tid = blockIdx.x * 256 + threadIdx.x;   // 32768
  const int l = tid & 63;
  const int i = (tid >> 6) & 7;
  const int s = tid >> 9;
  const int n = i * 32 + (l & 31);
  const float* w = W1 + (size_t)s * 72 * 256;
  u16x8 v;
#pragma unroll
  for (int j = 0; j < 8; ++j) v[j] = 0;
  if (l < 32) {
#pragma unroll
    for (int j = 0; j < 8; ++j) v[j] = f2bf(w[(64 + j) * 256 + n]);
  } else {
    v[0] = f2bf(w[s * 256 + n] + b1[s * 256 + n]);  // c1, rides k=8 (ones slot)
  }
  ((u16x8*)a1b)[tid] = v;
}

// ---- P5: layer-3 A-frags (verified) ---------------------------------------
__global__ __launch_bounds__(256) void prep_wpg_k(
    const float* __restrict__ Wp, const float* __restrict__ g2,
    const float* __restrict__ be2, const float* __restrict__ bp,
    unsigned short* __restrict__ wpg) {
  const int tid = blockIdx.x * 256 + threadIdx.x;   // 69632
  const int l = tid & 63;
  const int r = tid >> 6;
  const int t = r % 17;
  const int s = r / 17;
  const int a = l & 31;
  const int h = l >> 5;
  u16x8 v;
#pragma unroll
  for (int j = 0; j < 8; ++j) v[j] = 0;
  if (t < 16) {
    if (a < 16) {
      const float* w = Wp + (size_t)s * 4096;       // [k][a]
      const float* g = g2 + s * 256;
#pragma unroll
      for (int j = 0; j < 8; ++j) {
        const int k = t * 16 + h * 8 + j;
        v[j] = f2bf(w[k * 16 + a] * g[k]);
      }
    }
  } else if (h == 0 && a < 16) {
    const float* w = Wp + (size_t)s * 4096;
    float up = 0.f, cp = 0.f;
#pragma unroll 8
    for (int k = 0; k < 256; ++k) {
      const float wk = w[k * 16 + a];
      up = fmaf(wk, g2[s * 256 + k], up);
      cp = fmaf(wk, be2[s * 256 + k], cp);
    }
    cp += bp[s * 16 + a];
    v[0] = f2bf(up); v[1] = f2bf(cp);
  }
  ((u16x8*)wpg)[tid] = v;
}

// ---- pack one 32-n f32x16 tile -> two B-frags (pair-swap, verified) -------
__device__ __forceinline__ void pack_tile(const f32x16& a,
                                          unsigned* f0, unsigned* f1) {
  unsigned w0 = cvtpk(a[0], a[1]),   w1 = cvtpk(a[2], a[3]);
  unsigned w2 = cvtpk(a[4], a[5]),   w3 = cvtpk(a[6], a[7]);
  unsigned w4 = cvtpk(a[8], a[9]),   w5 = cvtpk(a[10], a[11]);
  unsigned w6 = cvtpk(a[12], a[13]), w7 = cvtpk(a[14], a[15]);
  swap2(w0, w2); swap2(w1, w3); swap2(w4, w6); swap2(w5, w7);
  f0[0] = w0; f0[1] = w1; f0[2] = w2; f0[3] = w3;
  f1[0] = w4; f1[1] = w5; f1[2] = w6; f1[3] = w7;
}

// ---- main fused kernel: in-wave pipe interleaving -------------------------
__global__ __launch_bounds__(512, 2) void actor_main(
    const float* __restrict__ x, const int* __restrict__ midx,
    const unsigned short* __restrict__ w2g, const unsigned* __restrict__ uc2,
    const unsigned short* __restrict__ a1b, const unsigned short* __restrict__ wpg,
    float* __restrict__ out) {
  extern __shared__ char lds[];                 // 128KB W2g blob
  const int tid = threadIdx.x;
  const int wv = tid >> 6;
  const int l = tid & 63;
  const int bl = l & 31;
  const int h = l >> 5;
  const int s = blockIdx.x >> 2;
  const int rowstart = (blockIdx.x & 3) << 12;

  { // stage W2g blob, linear, conflict-free
    const u32x4* src = (const u32x4*)(w2g + (size_t)s * 65536);
    u32x4* dst = (u32x4*)lds;
#pragma unroll
    for (int i = 0; i < 16; ++i) dst[i * 512 + tid] = src[i * 512 + tid];
  }

  unsigned aext[8];
#pragma unroll
  for (int i = 0; i < 8; ++i) {
    const unsigned t = uc2[(s * 8 + i) * 32 + bl];
    aext[i] = h ? 0u : t;
  }
  const int4 mi4 = ((const int4*)(midx + s * 8))[h];
  const bf16x8* A1 = ((const bf16x8*)a1b) + (size_t)(s * 8) * 64 + l;
  const bf16x8* A3 = ((const bf16x8*)wpg) + (size_t)(s * 17) * 64 + l;
  const char* ldsl = lds + (l << 4);

  const float* xbase = x + (size_t)(rowstart + wv * 32 + bl) * 64;

  // prologue gather (iter 0)
  float ga = mi4.x < 0 ? 0.f : xbase[mi4.x];
  float gb = mi4.y < 0 ? 0.f : xbase[mi4.y];
  float gc = mi4.z < 0 ? 0.f : xbase[mi4.z];
  float gd = mi4.w < 0 ? 0.f : xbase[mi4.w];

  __syncthreads();   // only barrier: W2g staged

  for (int it = 0; it < 16; ++it) {
    const int row = rowstart + it * 256 + wv * 32 + bl;

    // ---- build layer-1 B-frag from current gather ----------------------
    unsigned oa0, ob0, oa1, ob1;
    plswap(cvtpk(ga, gb), oa0, ob0);
    plswap(cvtpk(gc, gd), oa1, ob1);
    U8 B1;
    B1.u[0] = h ? 0x00003F80u : oa0;   // h=1: k=8 -> 1.0 (c1 slot)
    B1.u[1] = h ? 0u : oa1;
    B1.u[2] = h ? 0u : ob0;
    B1.u[3] = h ? 0u : ob1;

    // ---- prefetch next iteration's gather (latency hidden by full iter) -
    {
      const float* xn = xbase + (size_t)(((it + 1) & 15) * 256) * 64;
      ga = mi4.x < 0 ? 0.f : xn[mi4.x];
      gb = mi4.y < 0 ? 0.f : xn[mi4.y];
      gc = mi4.z < 0 ? 0.f : xn[mi4.z];
      gd = mi4.w < 0 ? 0.f : xn[mi4.w];
    }

    // ---- phase A: fused L1 -> leaky/stats/pack -> L2, interleaved ------
    float s0 = 0.f, s1 = 0.f, q0 = 0.f, q1 = 0.f;
    f32x16 acc2[8];
    bf16x8 a1n = A1[0];              // A1 frag prefetch (L2-hot)
    bf16x8 Afc[8];
#pragma unroll
    for (int j = 0; j < 8; ++j)      // ds prefetch for t=0
      Afc[j] = *(const bf16x8*)(ldsl + ((j * 16 + 0) << 10));

#pragma unroll
    for (int i = 0; i < 8; ++i) {
      // L1 MFMA for this tile (MAI pipe; short latency to first use)
      f32x16 z = {};
      const f32x16 accP = MFMA32(a1n, B1.v, z);
      if (i < 7) a1n = A1[(i + 1) * 64];          // prefetch next A1 frag

      // leaky + stats + pack (VALU; overlaps in-flight ds/MAI)
      f32x16 yv;
#pragma unroll
      for (int r = 0; r < 16; ++r) {
        float v = accP[r];
        v = fmaxf(v, 0.01f * v);
        yv[r] = v;
        if (r & 1) { s1 += v; q1 = fmaf(v, v, q1); }
        else       { s0 += v; q0 = fmaf(v, v, q0); }
      }
      U8 Bf0, Bf1;
      pack_tile(yv, Bf0.u, Bf1.u);

      // k-step t=2i with prefetched Af
#pragma unroll
      for (int j = 0; j < 8; ++j) {
        if (i == 0) { f32x16 zz = {}; acc2[j] = MFMA32(Afc[j], Bf0.v, zz); }
        else        { acc2[j] = MFMA32(Afc[j], Bf0.v, acc2[j]); }
      }
      // load + k-step t=2i+1 (MAI of t=2i hides part of the ds latency)
      bf16x8 Afn[8];
#pragma unroll
      for (int j = 0; j < 8; ++j)
        Afn[j] = *(const bf16x8*)(ldsl + ((j * 16 + 2 * i + 1) << 10));
#pragma unroll
      for (int j = 0; j < 8; ++j) acc2[j] = MFMA32(Afn[j], Bf1.v, acc2[j]);
      // prefetch t=2i+2 for next step
      if (i < 7) {
#pragma unroll
        for (int j = 0; j < 8; ++j)
          Afc[j] = *(const bf16x8*)(ldsl + ((j * 16 + 2 * i + 2) << 10));
      }
    }

    // ---- LN1 stats finalize + rank-1 correction k-step ------------------
    float sum = s0 + s1, ssq = q0 + q1;
    sum += __shfl_xor(sum, 32, 64);
    ssq += __shfl_xor(ssq, 32, 64);
    const float m1 = sum * 0.00390625f;
    const float var1 = fmaf(ssq, 0.00390625f, -m1 * m1) + LNEPS;
    const float rho1 = rsqrtf(var1);
    const float std1 = var1 * rho1;               // = 1/rho1
    const unsigned be2w = cvtpk(-m1, std1);
    // prefetch first layer-3 A-frags (VMEM, hidden under corr MFMAs)
    bf16x8 p0 = A3[0], p1 = A3[64];
    {
      U8 Bx; Bx.u[0] = h ? 0u : be2w; Bx.u[1] = 0; Bx.u[2] = 0; Bx.u[3] = 0;
#pragma unroll
      for (int i = 0; i < 8; ++i) {
        U8 Ax; Ax.u[0] = aext[i]; Ax.u[1] = 0; Ax.u[2] = 0; Ax.u[3] = 0;
        acc2[i] = MFMA32(Ax.v, Bx.v, acc2[i]);
      }
    }

    // ---- phase B: fused leaky/stats2/pack + layer-3 (A3 prefetch) -------
    f32x16 a3a = {}, a3b = {};
    s0 = s1 = q0 = q1 = 0.f;
#pragma unroll
    for (int i = 0; i < 8; ++i) {
      bf16x8 n0, n1;
      if (i < 7) { n0 = A3[(2 * i + 2) * 64]; n1 = A3[(2 * i + 3) * 64]; }
      else       { n0 = A3[16 * 64]; n1 = p1; }
      f32x16 yv;
#pragma unroll
      for (int r = 0; r < 16; ++r) {
        float v = acc2[i][r];
        v = fmaxf(v, 0.01f * v);
        yv[r] = v;
        if (r & 1) { s1 += v; q1 = fmaf(v, v, q1); }
        else       { s0 += v; q0 = fmaf(v, v, q0); }
      }
      U8 Bf0, Bf1;
      pack_tile(yv, Bf0.u, Bf1.u);
      a3a = MFMA32(p0, Bf0.v, a3a);
      a3b = MFMA32(p1, Bf1.v, a3b);
      p0 = n0; p1 = n1;
    }
    float sum2 = s0 + s1, ssq2 = q0 + q1;
    sum2 += __shfl_xor(sum2, 32, 64);
    ssq2 += __shfl_xor(ssq2, 32, 64);
    const float mp = sum2 * 0.00390625f;
    const float qp = ssq2 * 0.00390625f;
    const float var2 = rho1 * rho1 * fmaf(-mp, mp, qp) + LNEPS;
    const float rho2 = rsqrtf(var2);
    const float sigma = rho1 * rho2;
    const float inv = var2 * rho2 * std1;         // = 1/sigma
    const unsigned be3w = cvtpk(-mp, inv);
    { // LN2 rank-1 correction k-step (p0 holds A3[16*64])
      U8 Bx; Bx.u[0] = h ? 0u : be3w; Bx.u[1] = 0; Bx.u[2] = 0; Bx.u[3] = 0;
      a3a = MFMA32(p0, Bx.v, a3a);
    }

    // ---- log-softmax + store --------------------------------------------
    float lg[8];
#pragma unroll
    for (int r = 0; r < 8; ++r) lg[r] = sigma * (a3a[r] + a3b[r]);
    float mx = fmaxf(fmaxf(fmaxf(lg[0], lg[1]), fmaxf(lg[2], lg[3])),
                     fmaxf(fmaxf(lg[4], lg[5]), fmaxf(lg[6], lg[7])));
    mx = fmaxf(mx, __shfl_xor(mx, 32, 64));
    float es = 0.f;
#pragma unroll
    for (int r = 0; r < 8; ++r) es += __expf(lg[r] - mx);
    es += __shfl_xor(es, 32, 64);
    const float lse = mx + __logf(es);

    const size_t ob = (((size_t)row << 6) + s) * 16 + (h << 2);
    f32x4 v0 = {lg[0], lg[1], lg[2], lg[3]};
    f32x4 v1 = {lg[4], lg[5], lg[6], lg[7]};
    *(f32x4*)(out + ob) = v0;
    *(f32x4*)(out + ob + 8) = v1;
    f32x4 w0 = {lg[0] - lse, lg[1] - lse, lg[2] - lse, lg[3] - lse};
    f32x4 w1 = {lg[4] - lse, lg[5] - lse, lg[6] - lse, lg[7] - lse};
    *(f32x4*)(out + 16777216 + ob) = w0;
    *(f32x4*)(out + 16777216 + ob + 8) = w1;
  }
}

extern "C" void kernel_launch(void* const* d_in, const int* in_sizes, int n_in,
                              void* d_out, int out_size, void* d_ws, size_t ws_size,
                              hipStream_t stream) {
  const float* x    = (const float*)d_in[0];
  const int*   oidx = (const int*)d_in[1];
  const unsigned* omask = (const unsigned*)d_in[2];
  const float* W1 = (const float*)d_in[3];
  const float* b1 = (const float*)d_in[4];
  const float* g1 = (const float*)d_in[5];
  const float* be1 = (const float*)d_in[6];
  const float* W2 = (const float*)d_in[7];
  const float* b2 = (const float*)d_in[8];
  const float* g2 = (const float*)d_in[9];
  const float* be2 = (const float*)d_in[10];
  const float* Wp = (const float*)d_in[11];
  const float* bp = (const float*)d_in[12];
  float* out = (float*)d_out;

  char* ws = (char*)d_ws;
  unsigned short* wsW2G = (unsigned short*)(ws + WS_W2G);
  unsigned short* wsA1  = (unsigned short*)(ws + WS_A1);
  unsigned short* wsWPG = (unsigned short*)(ws + WS_WPG);
  unsigned*       wsUC2 = (unsigned*)(ws + WS_UC2);
  int*            wsMIDX = (int*)(ws + WS_MIDX);

  prep_midx_k<<<1, 512, 0, stream>>>(oidx, omask, wsMIDX);
  prep_w2g_k<<<2048, 256, 0, stream>>>(W2, g1, wsW2G);
  prep_uc2_k<<<64, 256, 0, stream>>>(W2, g1, be1, b2, wsUC2);
  prep_a1_k<<<128, 256, 0, stream>>>(W1, b1, wsA1);
  prep_wpg_k<<<272, 256, 0, stream>>>(Wp, g2, be2, bp, wsWPG);

  hipFuncSetAttribute((const void*)actor_main,
                      hipFuncAttributeMaxDynamicSharedMemorySize, 131072);
  actor_main<<<256, 512, 131072, stream>>>(
      x, wsMIDX, wsW2G, wsUC2, wsA1, wsWPG, out);
}